// Round 6
// baseline (160.046 us; speedup 1.0000x reference)
//
#include <hip/hip_runtime.h>
#include <math.h>

#define NPTS 21
#define FLB  63           // floats per batch per tensor (21*3)
#define BPB  64           // batches per chunk = one batch per thread
#define THREADS 64        // single wave per block
#define NVEC (BPB * FLB / 4)           // 1008 float4 per tensor-chunk
#define FULL_ROUNDS (NVEC / THREADS)   // 15
#define TAIL_LANES  (NVEC % THREADS)   // 48
#define GRID 1280                      // 5 one-wave blocks per CU (LDS-limited)

typedef __attribute__((address_space(3))) float       lds_f;
typedef __attribute__((address_space(3))) void        lds_v;
typedef const __attribute__((address_space(1))) void  gbl_v;

// direct global->LDS DMA, 16B per lane; LDS dest is wave-uniform base + lane*16
__device__ __forceinline__ void async_cp16(const float* g, lds_f* l) {
    __builtin_amdgcn_global_load_lds((gbl_v*)g, (lds_v*)l, 16, 0, 0);
}

// stage one 16128B tensor-chunk: exactly 16 VMEM instructions (vmcnt +16)
__device__ __forceinline__ void stage_chunk(const float* gbase, lds_f* lbuf, int tid) {
    #pragma unroll
    for (int j = 0; j < FULL_ROUNDS; ++j)
        async_cp16(gbase + 4 * (j * THREADS + tid), lbuf + 4 * (j * THREADS));
    if (tid < TAIL_LANES)   // 48 lanes active -> still one instruction, always issued
        async_cp16(gbase + 4 * (FULL_ROUNDS * THREADS + tid),
                   lbuf + 4 * (FULL_ROUNDS * THREADS));
}

__global__ __launch_bounds__(THREADS, 2)
void pa_mpjpe(const float* __restrict__ pred,
              const float* __restrict__ targ,
              float* __restrict__ ws,
              int nchunk)
{
    // two chunk buffers, stride-63 per-thread layout (odd stride: 2-way aliasing = free)
    __shared__ __align__(16) float sp_[BPB * FLB];   // 16128 B  pred chunk
    __shared__ __align__(16) float st_[BPB * FLB];   // 16128 B  targ chunk
    // cast ONCE at declaration (provenance-visible -> folds; all LDS math in AS(3))
    lds_f* sp = (lds_f*)sp_;
    lds_f* st = (lds_f*)st_;

    const int tid  = threadIdx.x;
    const int base = tid * FLB;
    const float invN = 1.0f / (float)NPTS;
    float block_err = 0.0f;

    int c = blockIdx.x;
    if (c < nchunk) {                    // prologue: fill the pipeline
        stage_chunk(pred + (size_t)c * (BPB * FLB), sp, tid);
        stage_chunk(targ + (size_t)c * (BPB * FLB), st, tid);
    }

    for (; c < nchunk; c += GRID) {
        const int cn = c + GRID;

        // pred_c = oldest 16 of <=32 outstanding -> done once <=16 remain
        asm volatile("s_waitcnt vmcnt(16)" ::: "memory");

        // ---- pass 1: pred -> registers, raw moments ----
        float y[NPTS][3];
        float sy0 = 0.f, sy1 = 0.f, sy2 = 0.f, syy = 0.f;
        #pragma unroll
        for (int n = 0; n < NPTS; ++n) {
            float a = sp[base + 3*n + 0];
            float b = sp[base + 3*n + 1];
            float d = sp[base + 3*n + 2];
            y[n][0] = a; y[n][1] = b; y[n][2] = d;
            sy0 += a; sy1 += b; sy2 += d;
            syy = fmaf(a, a, fmaf(b, b, fmaf(d, d, syy)));
        }
        // all sp ds_reads complete -> safe to overwrite sp with next pred
        asm volatile("s_waitcnt lgkmcnt(0)" ::: "memory");
        if (cn < nchunk) {
            stage_chunk(pred + (size_t)cn * (BPB * FLB), sp, tid);
            // targ_c now the oldest 16 of 32 outstanding
            asm volatile("s_waitcnt vmcnt(16)" ::: "memory");
        } else {
            asm volatile("s_waitcnt vmcnt(0)" ::: "memory");   // no prefetch issued
        }

        // ---- pass 2: targ stats + raw cross-covariance ----
        float sx0 = 0.f, sx1 = 0.f, sx2 = 0.f;
        float m00=0,m01=0,m02=0, m10=0,m11=0,m12=0, m20=0,m21=0,m22=0;
        #pragma unroll
        for (int n = 0; n < NPTS; ++n) {
            float a = st[base + 3*n + 0];
            float b = st[base + 3*n + 1];
            float d = st[base + 3*n + 2];
            sx0 += a; sx1 += b; sx2 += d;
            float u = y[n][0], v = y[n][1], w = y[n][2];
            m00 = fmaf(a,u,m00); m01 = fmaf(a,v,m01); m02 = fmaf(a,w,m02);
            m10 = fmaf(b,u,m10); m11 = fmaf(b,v,m11); m12 = fmaf(b,w,m12);
            m20 = fmaf(d,u,m20); m21 = fmaf(d,v,m21); m22 = fmaf(d,w,m22);
        }

        float mux0 = sx0*invN, mux1 = sx1*invN, mux2 = sx2*invN;
        float muy0 = sy0*invN, muy1 = sy1*invN, muy2 = sy2*invN;
        float ny2  = syy - (sy0*sy0 + sy1*sy1 + sy2*sy2) * invN;   // ||Y0||_F^2
        float c00 = m00 - sx0*sy0*invN, c01 = m01 - sx0*sy1*invN, c02 = m02 - sx0*sy2*invN;
        float c10 = m10 - sx1*sy0*invN, c11 = m11 - sx1*sy1*invN, c12 = m12 - sx1*sy2*invN;
        float c20 = m20 - sx2*sy0*invN, c21 = m21 - sx2*sy1*invN, c22 = m22 - sx2*sy2*invN;

        // ---- polar factor of A = Mc^T via det-scaled Newton (Q = V U^T) ----
        float q00=c00, q01=c10, q02=c20,
              q10=c01, q11=c11, q12=c21,
              q20=c02, q21=c12, q22=c22;
        #pragma unroll
        for (int it = 0; it < 8; ++it) {
            float C00 = q11*q22 - q12*q21;
            float C01 = q12*q20 - q10*q22;
            float C02 = q10*q21 - q11*q20;
            float C10 = q02*q21 - q01*q22;
            float C11 = q00*q22 - q02*q20;
            float C12 = q01*q20 - q00*q21;
            float C20 = q01*q12 - q02*q11;
            float C21 = q02*q10 - q00*q12;
            float C22 = q00*q11 - q01*q10;
            float det = q00*C00 + q01*C01 + q02*C02;
            float ad  = fmaxf(fabsf(det), 1e-30f);
            float sdet = copysignf(ad, det);
            float g  = __expf(0.333333333f * __logf(ad));   // |det|^{1/3}
            float ha = 0.5f / g;
            float hb = 0.5f * g / sdet;
            q00 = ha*q00 + hb*C00; q01 = ha*q01 + hb*C01; q02 = ha*q02 + hb*C02;
            q10 = ha*q10 + hb*C10; q11 = ha*q11 + hb*C11; q12 = ha*q12 + hb*C12;
            q20 = ha*q20 + hb*C20; q21 = ha*q21 + hb*C21; q22 = ha*q22 + hb*C22;
        }

        float trP = q00*c00 + q01*c10 + q02*c20
                  + q10*c01 + q11*c11 + q12*c21
                  + q20*c02 + q21*c12 + q22*c22;     // sum of singular values
        float k = trP / ny2;
        float r00=k*q00, r01=k*q01, r02=k*q02;
        float r10=k*q10, r11=k*q11, r12=k*q12;
        float r20=k*q20, r21=k*q21, r22=k*q22;

        // ---- error pass (re-read targ from LDS) ----
        float errsum = 0.0f;
        #pragma unroll
        for (int n = 0; n < NPTS; ++n) {
            float xa = st[base + 3*n + 0];
            float xb = st[base + 3*n + 1];
            float xc = st[base + 3*n + 2];
            float u = y[n][0] - muy0, v = y[n][1] - muy1, w = y[n][2] - muy2;
            float z0 = fmaf(u, r00, fmaf(v, r10, fmaf(w, r20, mux0))) - xa;
            float z1 = fmaf(u, r01, fmaf(v, r11, fmaf(w, r21, mux1))) - xb;
            float z2 = fmaf(u, r02, fmaf(v, r12, fmaf(w, r22, mux2))) - xc;
            errsum += sqrtf(fmaf(z0, z0, fmaf(z1, z1, z2*z2)));
        }
        block_err += errsum;

        // all st ds_reads complete -> safe to overwrite st with next targ
        asm volatile("s_waitcnt lgkmcnt(0)" ::: "memory");
        if (cn < nchunk)
            stage_chunk(targ + (size_t)cn * (BPB * FLB), st, tid);
    }

    // ---- single-wave reduction, one plain store per block ----
    #pragma unroll
    for (int off = 32; off > 0; off >>= 1) block_err += __shfl_down(block_err, off, 64);
    if (tid == 0) ws[blockIdx.x] = block_err;
}

// single block: reduce the per-block partials, write the final mean
__global__ __launch_bounds__(256)
void pa_reduce(const float* __restrict__ ws, float* __restrict__ out,
               int nblk, float inv_total)
{
    __shared__ float sw[4];
    float s = 0.0f;
    for (int i = threadIdx.x; i < nblk; i += 256) s += ws[i];
    #pragma unroll
    for (int off = 32; off > 0; off >>= 1) s += __shfl_down(s, off, 64);
    if ((threadIdx.x & 63) == 0) sw[threadIdx.x >> 6] = s;
    __syncthreads();
    if (threadIdx.x == 0)
        out[0] = (sw[0] + sw[1] + sw[2] + sw[3]) * inv_total;
}

extern "C" void kernel_launch(void* const* d_in, const int* in_sizes, int n_in,
                              void* d_out, int out_size, void* d_ws, size_t ws_size,
                              hipStream_t stream)
{
    const float* pred = (const float*)d_in[0];   // pred_kp3d   [B,21,3] f32
    const float* targ = (const float*)d_in[1];   // target_kp3d [B,21,3] f32
    float* out = (float*)d_out;
    float* ws  = (float*)d_ws;

    int B = in_sizes[0] / FLB;                   // 262144 (divisible by BPB=64)
    int nchunk = B / BPB;                        // 4096
    float inv_total = 1.0f / ((float)B * (float)NPTS);

    pa_mpjpe<<<GRID, THREADS, 0, stream>>>(pred, targ, ws, nchunk);
    pa_reduce<<<1, 256, 0, stream>>>(ws, out, GRID, inv_total);
}

// Round 7
// 159.891 us; speedup vs baseline: 1.0010x; 1.0010x over previous
//
#include <hip/hip_runtime.h>
#include <math.h>

#define NPTS 21
#define FLB  63            // floats per batch per tensor (21*3), contiguous per batch

// One thread = one batch. No LDS, no barriers: each thread loads its own
// contiguous 252B span with wide loads (4B-aligned dwordx4 is legal on gfx950),
// keeps both point sets in VGPRs, computes the whole Procrustes chain locally.
__global__ __launch_bounds__(64, 2)   // VGPR cap 256: ~126 data floats + temps, no spill
void pa_mpjpe(const float* __restrict__ pred,
              const float* __restrict__ targ,
              float* __restrict__ ws,
              int B)
{
    const int b = blockIdx.x * 64 + threadIdx.x;
    float errsum = 0.0f;

    if (b < B) {
        const float* gp = pred + (size_t)b * FLB;
        const float* gt = targ + (size_t)b * FLB;

        // ---- wide register loads: 15x16B + 1x12B per tensor, all independent ----
        float yv[FLB];   // pred
        float xv[FLB];   // targ
        #pragma unroll
        for (int i = 0; i < 15; ++i) __builtin_memcpy(&yv[4*i], gp + 4*i, 16);
        __builtin_memcpy(&yv[60], gp + 60, 12);
        #pragma unroll
        for (int i = 0; i < 15; ++i) __builtin_memcpy(&xv[4*i], gt + 4*i, 16);
        __builtin_memcpy(&xv[60], gt + 60, 12);

        // ---- raw moments of pred ----
        float sy0 = 0.f, sy1 = 0.f, sy2 = 0.f, syy = 0.f;
        #pragma unroll
        for (int n = 0; n < NPTS; ++n) {
            float a = yv[3*n+0], bb = yv[3*n+1], d = yv[3*n+2];
            sy0 += a; sy1 += bb; sy2 += d;
            syy = fmaf(a, a, fmaf(bb, bb, fmaf(d, d, syy)));
        }

        // ---- targ stats + raw cross-covariance M[i][j] = sum_n x_i * y_j ----
        float sx0 = 0.f, sx1 = 0.f, sx2 = 0.f;
        float m00=0,m01=0,m02=0, m10=0,m11=0,m12=0, m20=0,m21=0,m22=0;
        #pragma unroll
        for (int n = 0; n < NPTS; ++n) {
            float a = xv[3*n+0], bb = xv[3*n+1], d = xv[3*n+2];
            float u = yv[3*n+0], v = yv[3*n+1], w = yv[3*n+2];
            sx0 += a; sx1 += bb; sx2 += d;
            m00 = fmaf(a,u,m00); m01 = fmaf(a,v,m01); m02 = fmaf(a,w,m02);
            m10 = fmaf(bb,u,m10); m11 = fmaf(bb,v,m11); m12 = fmaf(bb,w,m12);
            m20 = fmaf(d,u,m20); m21 = fmaf(d,v,m21); m22 = fmaf(d,w,m22);
        }

        const float invN = 1.0f / (float)NPTS;
        float mux0 = sx0*invN, mux1 = sx1*invN, mux2 = sx2*invN;
        float muy0 = sy0*invN, muy1 = sy1*invN, muy2 = sy2*invN;
        float ny2  = syy - (sy0*sy0 + sy1*sy1 + sy2*sy2) * invN;   // ||Y0||_F^2
        float c00 = m00 - sx0*sy0*invN, c01 = m01 - sx0*sy1*invN, c02 = m02 - sx0*sy2*invN;
        float c10 = m10 - sx1*sy0*invN, c11 = m11 - sx1*sy1*invN, c12 = m12 - sx1*sy2*invN;
        float c20 = m20 - sx2*sy0*invN, c21 = m21 - sx2*sy1*invN, c22 = m22 - sx2*sy2*invN;

        // ---- polar factor of A = Mc^T via det-scaled Newton (Q = V U^T,
        //      reflection allowed, matches scipy-style reference exactly) ----
        float q00=c00, q01=c10, q02=c20,
              q10=c01, q11=c11, q12=c21,
              q20=c02, q21=c12, q22=c22;
        #pragma unroll
        for (int it = 0; it < 8; ++it) {
            float C00 = q11*q22 - q12*q21;
            float C01 = q12*q20 - q10*q22;
            float C02 = q10*q21 - q11*q20;
            float C10 = q02*q21 - q01*q22;
            float C11 = q00*q22 - q02*q20;
            float C12 = q01*q20 - q00*q21;
            float C20 = q01*q12 - q02*q11;
            float C21 = q02*q10 - q00*q12;
            float C22 = q00*q11 - q01*q10;
            float det = q00*C00 + q01*C01 + q02*C02;
            float ad  = fmaxf(fabsf(det), 1e-30f);
            float sdet = copysignf(ad, det);
            float g  = __expf(0.333333333f * __logf(ad));   // |det|^{1/3}
            float ha = 0.5f / g;
            float hb = 0.5f * g / sdet;
            q00 = ha*q00 + hb*C00; q01 = ha*q01 + hb*C01; q02 = ha*q02 + hb*C02;
            q10 = ha*q10 + hb*C10; q11 = ha*q11 + hb*C11; q12 = ha*q12 + hb*C12;
            q20 = ha*q20 + hb*C20; q21 = ha*q21 + hb*C21; q22 = ha*q22 + hb*C22;
        }

        // tr(P) = <Q, A>_F = sum of singular values of Mc; scale k = trP/||Y0||^2
        float trP = q00*c00 + q01*c10 + q02*c20
                  + q10*c01 + q11*c11 + q12*c21
                  + q20*c02 + q21*c12 + q22*c22;
        float k = trP / ny2;
        float r00=k*q00, r01=k*q01, r02=k*q02;
        float r10=k*q10, r11=k*q11, r12=k*q12;
        float r20=k*q20, r21=k*q21, r22=k*q22;

        // ---- per-joint error, all operands in registers ----
        #pragma unroll
        for (int n = 0; n < NPTS; ++n) {
            float xa = xv[3*n+0], xb = xv[3*n+1], xc = xv[3*n+2];
            float u = yv[3*n+0] - muy0, v = yv[3*n+1] - muy1, w = yv[3*n+2] - muy2;
            float z0 = fmaf(u, r00, fmaf(v, r10, fmaf(w, r20, mux0))) - xa;
            float z1 = fmaf(u, r01, fmaf(v, r11, fmaf(w, r21, mux1))) - xb;
            float z2 = fmaf(u, r02, fmaf(v, r12, fmaf(w, r22, mux2))) - xc;
            errsum += sqrtf(fmaf(z0, z0, fmaf(z1, z1, z2*z2)));
        }
    }

    // ---- single-wave reduction, one plain store per block ----
    #pragma unroll
    for (int off = 32; off > 0; off >>= 1) errsum += __shfl_down(errsum, off, 64);
    if (threadIdx.x == 0) ws[blockIdx.x] = errsum;
}

// single block: reduce the per-block partials, write the final mean
__global__ __launch_bounds__(256)
void pa_reduce(const float* __restrict__ ws, float* __restrict__ out,
               int nblk, float inv_total)
{
    __shared__ float sw[4];
    float s = 0.0f;
    for (int i = threadIdx.x; i < nblk; i += 256) s += ws[i];
    #pragma unroll
    for (int off = 32; off > 0; off >>= 1) s += __shfl_down(s, off, 64);
    if ((threadIdx.x & 63) == 0) sw[threadIdx.x >> 6] = s;
    __syncthreads();
    if (threadIdx.x == 0)
        out[0] = (sw[0] + sw[1] + sw[2] + sw[3]) * inv_total;
}

extern "C" void kernel_launch(void* const* d_in, const int* in_sizes, int n_in,
                              void* d_out, int out_size, void* d_ws, size_t ws_size,
                              hipStream_t stream)
{
    const float* pred = (const float*)d_in[0];   // pred_kp3d   [B,21,3] f32
    const float* targ = (const float*)d_in[1];   // target_kp3d [B,21,3] f32
    float* out = (float*)d_out;
    float* ws  = (float*)d_ws;

    int B = in_sizes[0] / FLB;                   // 262144
    int grid = (B + 63) / 64;                    // 4096 one-wave blocks
    float inv_total = 1.0f / ((float)B * (float)NPTS);

    pa_mpjpe<<<grid, 64, 0, stream>>>(pred, targ, ws, B);
    pa_reduce<<<1, 256, 0, stream>>>(ws, out, grid, inv_total);
}

// Round 8
// 153.148 us; speedup vs baseline: 1.0450x; 1.0440x over previous
//
#include <hip/hip_runtime.h>
#include <math.h>

#define NPTS 21
#define FLB  63            // floats per batch per tensor (21*3)
#define BPB  32            // batches per block (2 lanes per batch)
#define THREADS 64         // single wave per block
#define KPL  11            // points per lane (h=0: 11, h=1: 10 + 1 masked)
#define CHUNK_FLOATS (BPB * FLB)       // 2016 floats = 8064 B
#define NV4 (CHUNK_FLOATS / 4)         // 504 float4
#define FULL_ROUNDS (NV4 / THREADS)    // 7
#define TAIL_LANES  (NV4 % THREADS)    // 56

typedef __attribute__((address_space(3))) float       lds_f;
typedef __attribute__((address_space(3))) void        lds_v;
typedef const __attribute__((address_space(1))) void  gbl_v;

// direct global->LDS DMA, 16B per lane; LDS dest is wave-uniform base + lane*16
__device__ __forceinline__ void async_cp16(const float* g, lds_f* l) {
    __builtin_amdgcn_global_load_lds((gbl_v*)g, (lds_v*)l, 16, 0, 0);
}

// stage one 8064B tensor-chunk: 8 VMEM instructions
__device__ __forceinline__ void stage_chunk(const float* gbase, lds_f* lbuf, int tid) {
    #pragma unroll
    for (int j = 0; j < FULL_ROUNDS; ++j)
        async_cp16(gbase + 4 * (j * THREADS + tid), lbuf + 4 * (j * THREADS));
    if (tid < TAIL_LANES)
        async_cp16(gbase + 4 * (FULL_ROUNDS * THREADS + tid),
                   lbuf + 4 * (FULL_ROUNDS * THREADS));
}

__global__ __launch_bounds__(THREADS, 4)   // VGPR cap 128; LDS 8064B -> 19 blocks/CU
void pa_mpjpe(const float* __restrict__ pred,
              const float* __restrict__ targ,
              float* __restrict__ ws,
              int nchunk)
{
    __shared__ __align__(16) float sb_[CHUNK_FLOATS];   // single 8064B buffer
    lds_f* sb = (lds_f*)sb_;                            // AS(3) from declaration

    const int tid = threadIdx.x;
    const int lb  = tid >> 1;          // local batch 0..31
    const int h   = tid & 1;           // which half of the 21 points
    const int base = lb * FLB;
    const int c = blockIdx.x;

    const float* gp = pred + (size_t)c * CHUNK_FLOATS;
    const float* gt = targ + (size_t)c * CHUNK_FLOATS;

    // ---- stage PRED chunk ----
    stage_chunk(gp, sb, tid);
    asm volatile("s_waitcnt vmcnt(0)" ::: "memory");
    __syncthreads();                    // 1-wave block: no s_barrier emitted

    // ---- pass 1: my half of pred -> registers, partial moments ----
    float y[KPL][3];
    float sy0 = 0.f, sy1 = 0.f, sy2 = 0.f, syy = 0.f;
    #pragma unroll
    for (int k = 0; k < KPL; ++k) {
        int   n  = h * KPL + k;
        float m  = (n < NPTS) ? 1.0f : 0.0f;
        int   nn = (n < NPTS) ? n : (NPTS - 1);
        float a = sb[base + 3*nn + 0] * m;
        float b = sb[base + 3*nn + 1] * m;
        float d = sb[base + 3*nn + 2] * m;
        y[k][0] = a; y[k][1] = b; y[k][2] = d;
        sy0 += a; sy1 += b; sy2 += d;
        syy = fmaf(a, a, fmaf(b, b, fmaf(d, d, syy)));
    }
    // combine lane-pair partials (full-batch sums in both lanes)
    sy0 += __shfl_xor(sy0, 1, 64);
    sy1 += __shfl_xor(sy1, 1, 64);
    sy2 += __shfl_xor(sy2, 1, 64);
    syy += __shfl_xor(syy, 1, 64);

    // all pred ds_reads consumed; fence before overwriting the buffer
    asm volatile("s_waitcnt lgkmcnt(0)" ::: "memory");
    __syncthreads();

    // ---- stage TARG chunk into the same buffer ----
    stage_chunk(gt, sb, tid);
    asm volatile("s_waitcnt vmcnt(0)" ::: "memory");
    __syncthreads();

    // ---- pass 2: targ partial stats + partial cross-covariance ----
    float sx0 = 0.f, sx1 = 0.f, sx2 = 0.f;
    float m00=0,m01=0,m02=0, m10=0,m11=0,m12=0, m20=0,m21=0,m22=0;
    #pragma unroll
    for (int k = 0; k < KPL; ++k) {
        int   n  = h * KPL + k;
        float m  = (n < NPTS) ? 1.0f : 0.0f;
        int   nn = (n < NPTS) ? n : (NPTS - 1);
        float a = sb[base + 3*nn + 0] * m;
        float b = sb[base + 3*nn + 1] * m;
        float d = sb[base + 3*nn + 2] * m;
        float u = y[k][0], v = y[k][1], w = y[k][2];   // already masked
        sx0 += a; sx1 += b; sx2 += d;
        m00 = fmaf(a,u,m00); m01 = fmaf(a,v,m01); m02 = fmaf(a,w,m02);
        m10 = fmaf(b,u,m10); m11 = fmaf(b,v,m11); m12 = fmaf(b,w,m12);
        m20 = fmaf(d,u,m20); m21 = fmaf(d,v,m21); m22 = fmaf(d,w,m22);
    }
    sx0 += __shfl_xor(sx0, 1, 64);
    sx1 += __shfl_xor(sx1, 1, 64);
    sx2 += __shfl_xor(sx2, 1, 64);
    m00 += __shfl_xor(m00, 1, 64);  m01 += __shfl_xor(m01, 1, 64);  m02 += __shfl_xor(m02, 1, 64);
    m10 += __shfl_xor(m10, 1, 64);  m11 += __shfl_xor(m11, 1, 64);  m12 += __shfl_xor(m12, 1, 64);
    m20 += __shfl_xor(m20, 1, 64);  m21 += __shfl_xor(m21, 1, 64);  m22 += __shfl_xor(m22, 1, 64);

    const float invN = 1.0f / (float)NPTS;
    float mux0 = sx0*invN, mux1 = sx1*invN, mux2 = sx2*invN;
    float muy0 = sy0*invN, muy1 = sy1*invN, muy2 = sy2*invN;
    float ny2  = syy - (sy0*sy0 + sy1*sy1 + sy2*sy2) * invN;   // ||Y0||_F^2
    float c00 = m00 - sx0*sy0*invN, c01 = m01 - sx0*sy1*invN, c02 = m02 - sx0*sy2*invN;
    float c10 = m10 - sx1*sy0*invN, c11 = m11 - sx1*sy1*invN, c12 = m12 - sx1*sy2*invN;
    float c20 = m20 - sx2*sy0*invN, c21 = m21 - sx2*sy1*invN, c22 = m22 - sx2*sy2*invN;

    // ---- polar factor of A = Mc^T via det-scaled Newton (Q = V U^T,
    //      reflection allowed — matches the scipy-style reference) ----
    float q00=c00, q01=c10, q02=c20,
          q10=c01, q11=c11, q12=c21,
          q20=c02, q21=c12, q22=c22;
    #pragma unroll
    for (int it = 0; it < 8; ++it) {
        float C00 = q11*q22 - q12*q21;
        float C01 = q12*q20 - q10*q22;
        float C02 = q10*q21 - q11*q20;
        float C10 = q02*q21 - q01*q22;
        float C11 = q00*q22 - q02*q20;
        float C12 = q01*q20 - q00*q21;
        float C20 = q01*q12 - q02*q11;
        float C21 = q02*q10 - q00*q12;
        float C22 = q00*q11 - q01*q10;
        float det = q00*C00 + q01*C01 + q02*C02;
        float ad  = fmaxf(fabsf(det), 1e-30f);
        float sdet = copysignf(ad, det);
        float g  = __expf(0.333333333f * __logf(ad));   // |det|^{1/3}
        float ha = 0.5f / g;
        float hb = 0.5f * g / sdet;
        q00 = ha*q00 + hb*C00; q01 = ha*q01 + hb*C01; q02 = ha*q02 + hb*C02;
        q10 = ha*q10 + hb*C10; q11 = ha*q11 + hb*C11; q12 = ha*q12 + hb*C12;
        q20 = ha*q20 + hb*C20; q21 = ha*q21 + hb*C21; q22 = ha*q22 + hb*C22;
    }

    float trP = q00*c00 + q01*c10 + q02*c20
              + q10*c01 + q11*c11 + q12*c21
              + q20*c02 + q21*c12 + q22*c22;     // sum of singular values of Mc
    float kk = trP / ny2;
    float r00=kk*q00, r01=kk*q01, r02=kk*q02;
    float r10=kk*q10, r11=kk*q11, r12=kk*q12;
    float r20=kk*q20, r21=kk*q21, r22=kk*q22;

    // ---- error pass over my half of the points (targ still in LDS) ----
    float errsum = 0.0f;
    #pragma unroll
    for (int k = 0; k < KPL; ++k) {
        int   n  = h * KPL + k;
        float m  = (n < NPTS) ? 1.0f : 0.0f;
        int   nn = (n < NPTS) ? n : (NPTS - 1);
        float xa = sb[base + 3*nn + 0];
        float xb = sb[base + 3*nn + 1];
        float xc = sb[base + 3*nn + 2];
        float u = y[k][0] - muy0, v = y[k][1] - muy1, w = y[k][2] - muy2;
        float z0 = fmaf(u, r00, fmaf(v, r10, fmaf(w, r20, mux0))) - xa;
        float z1 = fmaf(u, r01, fmaf(v, r11, fmaf(w, r21, mux1))) - xb;
        float z2 = fmaf(u, r02, fmaf(v, r12, fmaf(w, r22, mux2))) - xc;
        errsum += m * sqrtf(fmaf(z0, z0, fmaf(z1, z1, z2*z2)));
    }

    // ---- single-wave reduction (covers both halves), one store per block ----
    #pragma unroll
    for (int off = 32; off > 0; off >>= 1) errsum += __shfl_down(errsum, off, 64);
    if (tid == 0) ws[blockIdx.x] = errsum;
}

// single block: reduce the per-block partials, write the final mean
__global__ __launch_bounds__(256)
void pa_reduce(const float* __restrict__ ws, float* __restrict__ out,
               int nblk, float inv_total)
{
    __shared__ float sw[4];
    float s = 0.0f;
    for (int i = threadIdx.x; i < nblk; i += 256) s += ws[i];
    #pragma unroll
    for (int off = 32; off > 0; off >>= 1) s += __shfl_down(s, off, 64);
    if ((threadIdx.x & 63) == 0) sw[threadIdx.x >> 6] = s;
    __syncthreads();
    if (threadIdx.x == 0)
        out[0] = (sw[0] + sw[1] + sw[2] + sw[3]) * inv_total;
}

extern "C" void kernel_launch(void* const* d_in, const int* in_sizes, int n_in,
                              void* d_out, int out_size, void* d_ws, size_t ws_size,
                              hipStream_t stream)
{
    const float* pred = (const float*)d_in[0];   // pred_kp3d   [B,21,3] f32
    const float* targ = (const float*)d_in[1];   // target_kp3d [B,21,3] f32
    float* out = (float*)d_out;
    float* ws  = (float*)d_ws;

    int B = in_sizes[0] / FLB;                   // 262144 (divisible by BPB=32)
    int nchunk = B / BPB;                        // 8192 one-wave blocks
    float inv_total = 1.0f / ((float)B * (float)NPTS);

    pa_mpjpe<<<nchunk, THREADS, 0, stream>>>(pred, targ, ws, nchunk);
    pa_reduce<<<1, 256, 0, stream>>>(ws, out, nchunk, inv_total);
}